// Round 1
// baseline (3878.997 us; speedup 1.0000x reference)
//
#include <hip/hip_runtime.h>
#include <hip/hip_bf16.h>

#define N_NODES 100000
#define N_EDGES 640000
#define DIM 128
#define N_LAYERS 3
#define N_GRAPHS 128
#define N_OUT 10

// ---------------- degree / norm ----------------

__global__ void init_deg(float* deg) {
    int i = blockIdx.x * blockDim.x + threadIdx.x;
    if (i < N_NODES) deg[i] = 1.0f;  // self-loop
}

__global__ void deg_scatter(const int* __restrict__ ei, float* deg) {
    int e = blockIdx.x * blockDim.x + threadIdx.x;
    if (e < N_EDGES) atomicAdd(&deg[ei[N_EDGES + e]], 1.0f);
}

__global__ void to_dinv(float* deg) {
    int i = blockIdx.x * blockDim.x + threadIdx.x;
    if (i < N_NODES) deg[i] = rsqrtf(deg[i]);  // deg >= 1 always
}

// ---------------- dense transform: out = in @ W  (N x 128 @ 128 x 128) ----------------

__global__ __launch_bounds__(256, 2) void gemm128(const float* __restrict__ in,
                                                  const float* __restrict__ W,
                                                  float* __restrict__ out) {
    __shared__ float Wl[DIM][DIM];   // 64 KB
    __shared__ float Hl[32][DIM];    // 16 KB

    // stage W into LDS (16384 floats, 4096 float4, 16 per thread)
    {
        const float4* W4 = (const float4*)W;
        float4* Wl4 = (float4*)&Wl[0][0];
        for (int i = threadIdx.x; i < DIM * DIM / 4; i += 256) Wl4[i] = W4[i];
    }

    const int c0 = (threadIdx.x & 31) * 4;   // 4 consecutive cols
    const int r0 = (threadIdx.x >> 5) * 4;   // 4 rows

    const int nchunks = N_NODES / 32;  // 3125 exactly
    for (int chunk = blockIdx.x; chunk < nchunks; chunk += gridDim.x) {
        const int row0 = chunk * 32;
        __syncthreads();  // previous-iter readers done before overwrite (also covers W stage)
        {
            const float4* in4 = (const float4*)(in + (size_t)row0 * DIM);
            float4* Hl4 = (float4*)&Hl[0][0];
            for (int i = threadIdx.x; i < 32 * DIM / 4; i += 256) Hl4[i] = in4[i];
        }
        __syncthreads();

        float acc[4][4];
        #pragma unroll
        for (int r = 0; r < 4; ++r)
            #pragma unroll
            for (int c = 0; c < 4; ++c) acc[r][c] = 0.0f;

        #pragma unroll 4
        for (int k = 0; k < DIM; ++k) {
            const float4 w = *(const float4*)&Wl[k][c0];
            const float h0 = Hl[r0 + 0][k];
            const float h1 = Hl[r0 + 1][k];
            const float h2 = Hl[r0 + 2][k];
            const float h3 = Hl[r0 + 3][k];
            acc[0][0] += h0 * w.x; acc[0][1] += h0 * w.y; acc[0][2] += h0 * w.z; acc[0][3] += h0 * w.w;
            acc[1][0] += h1 * w.x; acc[1][1] += h1 * w.y; acc[1][2] += h1 * w.z; acc[1][3] += h1 * w.w;
            acc[2][0] += h2 * w.x; acc[2][1] += h2 * w.y; acc[2][2] += h2 * w.z; acc[2][3] += h2 * w.w;
            acc[3][0] += h3 * w.x; acc[3][1] += h3 * w.y; acc[3][2] += h3 * w.z; acc[3][3] += h3 * w.w;
        }

        #pragma unroll
        for (int r = 0; r < 4; ++r) {
            float4 v; v.x = acc[r][0]; v.y = acc[r][1]; v.z = acc[r][2]; v.w = acc[r][3];
            *(float4*)&out[(size_t)(row0 + r0 + r) * DIM + c0] = v;
        }
    }
}

// ---------------- aggregation ----------------

// agg[i] = hw[i] * dinv[i]^2  (the self-loop message), pure write
__global__ void agg_init(const float* __restrict__ hw, const float* __restrict__ dinv,
                         float* __restrict__ agg) {
    int t = blockIdx.x * blockDim.x + threadIdx.x;  // N*D/4 threads
    if (t >= N_NODES * (DIM / 4)) return;
    int i = t / (DIM / 4);
    float di = dinv[i];
    float w = di * di;
    float4 v = ((const float4*)hw)[t];
    v.x *= w; v.y *= w; v.z *= w; v.w *= w;
    ((float4*)agg)[t] = v;
}

// one edge per 32 threads, 4 cols each
__global__ void edge_scatter(const int* __restrict__ ei, const float* __restrict__ dinv,
                             const float* __restrict__ hw, float* __restrict__ agg) {
    int t = blockIdx.x * blockDim.x + threadIdx.x;
    int e = t >> 5;
    int lane = t & 31;
    if (e >= N_EDGES) return;
    int s = ei[e];
    int d = ei[N_EDGES + e];
    float w = dinv[s] * dinv[d];
    const float4 v = *(const float4*)&hw[(size_t)s * DIM + lane * 4];
    float* ap = &agg[(size_t)d * DIM + lane * 4];
    atomicAdd(ap + 0, v.x * w);
    atomicAdd(ap + 1, v.y * w);
    atomicAdd(ap + 2, v.z * w);
    atomicAdd(ap + 3, v.w * w);
}

__global__ void bias_relu(float* __restrict__ h, const float* __restrict__ b) {
    int t = blockIdx.x * blockDim.x + threadIdx.x;  // N*D/4 threads
    if (t >= N_NODES * (DIM / 4)) return;
    int c = (t & (DIM / 4 - 1)) * 4;
    float4 v = ((float4*)h)[t];
    v.x = fmaxf(v.x + b[c + 0], 0.0f);
    v.y = fmaxf(v.y + b[c + 1], 0.0f);
    v.z = fmaxf(v.z + b[c + 2], 0.0f);
    v.w = fmaxf(v.w + b[c + 3], 0.0f);
    ((float4*)h)[t] = v;
}

// ---------------- pooling + head ----------------

__global__ void pool_scatter(const int* __restrict__ batch, const float* __restrict__ h,
                             float* __restrict__ pooled) {
    int t = blockIdx.x * blockDim.x + threadIdx.x;  // N*32 threads
    int i = t >> 5;
    int lane = t & 31;
    if (i >= N_NODES) return;
    int g = batch[i];
    const float4 v = *(const float4*)&h[(size_t)i * DIM + lane * 4];
    float* pp = &pooled[(size_t)g * DIM + lane * 4];
    atomicAdd(pp + 0, v.x);
    atomicAdd(pp + 1, v.y);
    atomicAdd(pp + 2, v.z);
    atomicAdd(pp + 3, v.w);
}

__global__ void mlp_head(const float* __restrict__ pooled, const float* __restrict__ Wm,
                         const float* __restrict__ bm, float* __restrict__ out) {
    int t = blockIdx.x * blockDim.x + threadIdx.x;
    if (t >= N_GRAPHS * N_OUT) return;
    int b = t / N_OUT;
    int o = t % N_OUT;
    float acc = bm[o];
    #pragma unroll 8
    for (int k = 0; k < DIM; ++k) acc += pooled[b * DIM + k] * Wm[k * N_OUT + o];
    out[t] = acc;
}

// ---------------- launch ----------------

extern "C" void kernel_launch(void* const* d_in, const int* in_sizes, int n_in,
                              void* d_out, int out_size, void* d_ws, size_t ws_size,
                              hipStream_t stream) {
    const float* x     = (const float*)d_in[0];
    const int*   ei    = (const int*)d_in[1];
    const int*   batch = (const int*)d_in[2];
    const float* Ws    = (const float*)d_in[3];
    const float* bs    = (const float*)d_in[4];
    const float* Wm    = (const float*)d_in[5];
    const float* bm    = (const float*)d_in[6];
    float* out = (float*)d_out;

    float* dinv   = (float*)d_ws;                       // N floats (as deg first)
    float* bufA   = dinv + N_NODES;                     // N*D floats (hw)
    float* bufB   = bufA + (size_t)N_NODES * DIM;       // N*D floats (agg / h)
    float* pooled = bufB + (size_t)N_NODES * DIM;       // B*D floats

    const int ndeg_blk = (N_NODES + 255) / 256;
    const int nedge_blk = (N_EDGES + 255) / 256;
    const int nelem_blk = (N_NODES * (DIM / 4) + 255) / 256;  // 12500

    init_deg<<<ndeg_blk, 256, 0, stream>>>(dinv);
    deg_scatter<<<nedge_blk, 256, 0, stream>>>(ei, dinv);
    to_dinv<<<ndeg_blk, 256, 0, stream>>>(dinv);

    const float* hin = x;
    for (int l = 0; l < N_LAYERS; ++l) {
        gemm128<<<1024, 256, 0, stream>>>(hin, Ws + (size_t)l * DIM * DIM, bufA);
        agg_init<<<nelem_blk, 256, 0, stream>>>(bufA, dinv, bufB);
        edge_scatter<<<N_EDGES * 32 / 256, 256, 0, stream>>>(ei, dinv, bufA, bufB);
        bias_relu<<<nelem_blk, 256, 0, stream>>>(bufB, bs + l * DIM);
        hin = bufB;
    }

    hipMemsetAsync(pooled, 0, N_GRAPHS * DIM * sizeof(float), stream);
    pool_scatter<<<N_NODES * 32 / 256 + 1, 256, 0, stream>>>(batch, bufB, pooled);
    mlp_head<<<(N_GRAPHS * N_OUT + 255) / 256, 256, 0, stream>>>(pooled, Wm, bm, out);
}

// Round 2
// 619.524 us; speedup vs baseline: 6.2613x; 6.2613x over previous
//
#include <hip/hip_runtime.h>
#include <hip/hip_bf16.h>

#define N_NODES 100000
#define N_EDGES 640000
#define DIM 128
#define N_LAYERS 3
#define N_GRAPHS 128
#define N_OUT 10
#define SCAN_BLK 1024  // elements per scan block (256 thr x 4)
#define N_SCAN_BLKS ((N_NODES + SCAN_BLK - 1) / SCAN_BLK)  // 98

// ---------------- degree / norm ----------------

__global__ void hist_dst(const int* __restrict__ ei, int* __restrict__ cnt) {
    int e = blockIdx.x * blockDim.x + threadIdx.x;
    if (e < N_EDGES) atomicAdd(&cnt[ei[N_EDGES + e]], 1);
}

__global__ void make_dinv(const int* __restrict__ cnt, float* __restrict__ dinv) {
    int i = blockIdx.x * blockDim.x + threadIdx.x;
    if (i < N_NODES) dinv[i] = rsqrtf((float)(cnt[i] + 1));  // +1 self-loop
}

// ---------------- exclusive scan (3 kernels) ----------------

__global__ void scan1(const int* __restrict__ cnt, int* __restrict__ off, int* __restrict__ bsum) {
    __shared__ int tmp[256];
    int base = blockIdx.x * SCAN_BLK + threadIdx.x * 4;
    int c[4];
    #pragma unroll
    for (int k = 0; k < 4; ++k) c[k] = (base + k < N_NODES) ? cnt[base + k] : 0;
    int tot = c[0] + c[1] + c[2] + c[3];
    tmp[threadIdx.x] = tot;
    __syncthreads();
    int val = tot;
    for (int d = 1; d < 256; d <<= 1) {
        int add = (threadIdx.x >= d) ? tmp[threadIdx.x - d] : 0;
        __syncthreads();
        val += add;
        tmp[threadIdx.x] = val;
        __syncthreads();
    }
    int ex = val - tot;  // exclusive prefix within block
    int e1 = ex + c[0], e2 = e1 + c[1], e3 = e2 + c[2];
    if (base + 0 < N_NODES) off[base + 0] = ex;
    if (base + 1 < N_NODES) off[base + 1] = e1;
    if (base + 2 < N_NODES) off[base + 2] = e2;
    if (base + 3 < N_NODES) off[base + 3] = e3;
    if (threadIdx.x == 255) bsum[blockIdx.x] = val;  // block total
}

__global__ void scan2(int* __restrict__ bsum) {
    if (threadIdx.x == 0 && blockIdx.x == 0) {
        int acc = 0;
        for (int i = 0; i < N_SCAN_BLKS; ++i) { int v = bsum[i]; bsum[i] = acc; acc += v; }
    }
}

__global__ void scan3(int* __restrict__ off, const int* __restrict__ bsum) {
    int i = blockIdx.x * blockDim.x + threadIdx.x;
    if (i < N_NODES) off[i] += bsum[i / SCAN_BLK];
    if (i == 0) off[N_NODES] = N_EDGES;
}

// ---------------- CSR fill ----------------

__global__ void fill_csr(const int* __restrict__ ei, const float* __restrict__ dinv,
                         const int* __restrict__ off, int* __restrict__ cursor,
                         int* __restrict__ csr_src, float* __restrict__ csr_w) {
    int e = blockIdx.x * blockDim.x + threadIdx.x;
    if (e >= N_EDGES) return;
    int s = ei[e], d = ei[N_EDGES + e];
    int pos = off[d] + atomicAdd(&cursor[d], 1);
    csr_src[pos] = s;
    csr_w[pos] = dinv[s] * dinv[d];
}

// ---------------- dense transform: out = in @ W  (N x 128 @ 128 x 128) ----------------

__global__ __launch_bounds__(256, 2) void gemm128(const float* __restrict__ in,
                                                  const float* __restrict__ W,
                                                  float* __restrict__ out) {
    __shared__ float Wl[DIM][DIM];   // 64 KB
    __shared__ float Hl[32][DIM];    // 16 KB

    {
        const float4* W4 = (const float4*)W;
        float4* Wl4 = (float4*)&Wl[0][0];
        for (int i = threadIdx.x; i < DIM * DIM / 4; i += 256) Wl4[i] = W4[i];
    }

    const int c0 = (threadIdx.x & 31) * 4;
    const int r0 = (threadIdx.x >> 5) * 4;

    const int nchunks = N_NODES / 32;  // 3125
    for (int chunk = blockIdx.x; chunk < nchunks; chunk += gridDim.x) {
        const int row0 = chunk * 32;
        __syncthreads();
        {
            const float4* in4 = (const float4*)(in + (size_t)row0 * DIM);
            float4* Hl4 = (float4*)&Hl[0][0];
            for (int i = threadIdx.x; i < 32 * DIM / 4; i += 256) Hl4[i] = in4[i];
        }
        __syncthreads();

        float acc[4][4];
        #pragma unroll
        for (int r = 0; r < 4; ++r)
            #pragma unroll
            for (int c = 0; c < 4; ++c) acc[r][c] = 0.0f;

        #pragma unroll 4
        for (int k = 0; k < DIM; ++k) {
            const float4 w = *(const float4*)&Wl[k][c0];
            const float h0 = Hl[r0 + 0][k];
            const float h1 = Hl[r0 + 1][k];
            const float h2 = Hl[r0 + 2][k];
            const float h3 = Hl[r0 + 3][k];
            acc[0][0] += h0 * w.x; acc[0][1] += h0 * w.y; acc[0][2] += h0 * w.z; acc[0][3] += h0 * w.w;
            acc[1][0] += h1 * w.x; acc[1][1] += h1 * w.y; acc[1][2] += h1 * w.z; acc[1][3] += h1 * w.w;
            acc[2][0] += h2 * w.x; acc[2][1] += h2 * w.y; acc[2][2] += h2 * w.z; acc[2][3] += h2 * w.w;
            acc[3][0] += h3 * w.x; acc[3][1] += h3 * w.y; acc[3][2] += h3 * w.z; acc[3][3] += h3 * w.w;
        }

        #pragma unroll
        for (int r = 0; r < 4; ++r) {
            float4 v; v.x = acc[r][0]; v.y = acc[r][1]; v.z = acc[r][2]; v.w = acc[r][3];
            *(float4*)&out[(size_t)(row0 + r0 + r) * DIM + c0] = v;
        }
    }
}

// ---------------- fused aggregate + bias + relu (+ pool on last layer) ----------------
// one wave64 per node; lane holds float2 of the 128-dim row

template<bool LAST>
__global__ __launch_bounds__(256) void gather_agg(const float* __restrict__ hw,
                                                  const float* __restrict__ dinv,
                                                  const int* __restrict__ off,
                                                  const int* __restrict__ csr_src,
                                                  const float* __restrict__ csr_w,
                                                  const float* __restrict__ bias,
                                                  const int* __restrict__ batch,
                                                  float* __restrict__ hout,
                                                  float* __restrict__ pooled) {
    int i = (blockIdx.x * blockDim.x + threadIdx.x) >> 6;  // node = wave id
    int lane = threadIdx.x & 63;
    if (i >= N_NODES) return;
    const float2* hw2 = (const float2*)hw;

    float di = dinv[i];
    float2 acc = hw2[i * 64 + lane];          // self-loop message
    float w_self = di * di;
    acc.x *= w_self; acc.y *= w_self;

    int beg = off[i], end = off[i + 1];
    int j = beg;
    for (; j + 1 < end; j += 2) {
        int s0 = csr_src[j], s1 = csr_src[j + 1];
        float w0 = csr_w[j], w1 = csr_w[j + 1];
        float2 v0 = hw2[s0 * 64 + lane];
        float2 v1 = hw2[s1 * 64 + lane];
        acc.x += w0 * v0.x + w1 * v1.x;
        acc.y += w0 * v0.y + w1 * v1.y;
    }
    if (j < end) {
        int s0 = csr_src[j];
        float w0 = csr_w[j];
        float2 v0 = hw2[s0 * 64 + lane];
        acc.x += w0 * v0.x;
        acc.y += w0 * v0.y;
    }

    acc.x = fmaxf(acc.x + bias[lane * 2 + 0], 0.0f);
    acc.y = fmaxf(acc.y + bias[lane * 2 + 1], 0.0f);

    if (!LAST) {
        ((float2*)hout)[i * 64 + lane] = acc;
    } else {
        int g = batch[i];
        atomicAdd(&pooled[g * DIM + lane * 2 + 0], acc.x);
        atomicAdd(&pooled[g * DIM + lane * 2 + 1], acc.y);
    }
}

// ---------------- head ----------------

__global__ void mlp_head(const float* __restrict__ pooled, const float* __restrict__ Wm,
                         const float* __restrict__ bm, float* __restrict__ out) {
    int t = blockIdx.x * blockDim.x + threadIdx.x;
    if (t >= N_GRAPHS * N_OUT) return;
    int b = t / N_OUT;
    int o = t % N_OUT;
    float acc = bm[o];
    #pragma unroll 8
    for (int k = 0; k < DIM; ++k) acc += pooled[b * DIM + k] * Wm[k * N_OUT + o];
    out[t] = acc;
}

// ---------------- launch ----------------

extern "C" void kernel_launch(void* const* d_in, const int* in_sizes, int n_in,
                              void* d_out, int out_size, void* d_ws, size_t ws_size,
                              hipStream_t stream) {
    const float* x     = (const float*)d_in[0];
    const int*   ei    = (const int*)d_in[1];
    const int*   batch = (const int*)d_in[2];
    const float* Ws    = (const float*)d_in[3];
    const float* bs    = (const float*)d_in[4];
    const float* Wm    = (const float*)d_in[5];
    const float* bm    = (const float*)d_in[6];
    float* out = (float*)d_out;

    // workspace carve-up (all regions 16B-aligned)
    char* p = (char*)d_ws;
    int*   cnt     = (int*)p;            p += N_NODES * 4;            // 400000
    float* dinv    = (float*)p;          p += N_NODES * 4;
    int*   csr_off = (int*)p;            p += (N_NODES + 16) * 4;     // N+1 used, padded
    int*   cursor  = (int*)p;            p += N_NODES * 4;
    int*   bsum    = (int*)p;            p += 128 * 4;
    int*   csr_src = (int*)p;            p += N_EDGES * 4;
    float* csr_w   = (float*)p;          p += N_EDGES * 4;
    float* bufA    = (float*)p;          p += (size_t)N_NODES * DIM * 4;
    float* bufB    = (float*)p;          p += (size_t)N_NODES * DIM * 4;
    float* pooled  = (float*)p;          p += N_GRAPHS * DIM * 4;

    const int nnode_blk = (N_NODES + 255) / 256;
    const int nedge_blk = (N_EDGES + 255) / 256;

    hipMemsetAsync(cnt, 0, N_NODES * 4, stream);
    hipMemsetAsync(cursor, 0, N_NODES * 4, stream);
    hipMemsetAsync(pooled, 0, N_GRAPHS * DIM * 4, stream);

    // degree + norm
    hist_dst<<<nedge_blk, 256, 0, stream>>>(ei, cnt);
    make_dinv<<<nnode_blk, 256, 0, stream>>>(cnt, dinv);

    // exclusive scan -> csr_off
    scan1<<<N_SCAN_BLKS, 256, 0, stream>>>(cnt, csr_off, bsum);
    scan2<<<1, 64, 0, stream>>>(bsum);
    scan3<<<nnode_blk, 256, 0, stream>>>(csr_off, bsum);

    // CSR fill
    fill_csr<<<nedge_blk, 256, 0, stream>>>(ei, dinv, csr_off, cursor, csr_src, csr_w);

    // layers
    const int gather_grid = (N_NODES * 64 + 255) / 256;  // one wave per node
    const float* hin = x;
    for (int l = 0; l < N_LAYERS; ++l) {
        gemm128<<<1024, 256, 0, stream>>>(hin, Ws + (size_t)l * DIM * DIM, bufA);
        if (l < N_LAYERS - 1) {
            gather_agg<false><<<gather_grid, 256, 0, stream>>>(bufA, dinv, csr_off, csr_src,
                                                               csr_w, bs + l * DIM, batch,
                                                               bufB, pooled);
            hin = bufB;
        } else {
            gather_agg<true><<<gather_grid, 256, 0, stream>>>(bufA, dinv, csr_off, csr_src,
                                                              csr_w, bs + l * DIM, batch,
                                                              nullptr, pooled);
        }
    }

    mlp_head<<<(N_GRAPHS * N_OUT + 255) / 256, 256, 0, stream>>>(pooled, Wm, bm, out);
}